// Round 5
// baseline (327.079 us; speedup 1.0000x reference)
//
#include <hip/hip_runtime.h>

#define HALF 128
#define NMAT 16384   // 128*128
#define NTOK 131072  // 32*4096

// ---------------------------------------------------------------------------
// K1: fused Cayley -> QT.  Q^T = N^{-1}(2I - N) = 2 N^{-1} - I,  N = I + A/2.
// Blocked Gauss-Jordan, panel b=16, 8 block-steps.
// Round-5 changes vs the verified round-4 kernel (same arithmetic order):
//  * outer s-loop NOT unrolled (round-4 lesson: 8x ~11KB unrolled body
//    thrashes the 32KB L1I with no co-resident waves to hide I-fetch)
//  * D-inverse replicated per wave (16-lane shuffle-GJ) -> no wave-0 park,
//    ONE barrier per step (Dinv goes to per-wave LDS scratch: wave-coherent)
//  * panel lanes: c-k0 == lane&15, so their Dinv column is their own dd[]
// ---------------------------------------------------------------------------
__global__ __launch_bounds__(512) void cayley_qt(const float* __restrict__ prim,
                                                 float* __restrict__ QT) {
    __shared__ __align__(16) float Xs[128 * 129];     // padded input stage
    __shared__ __align__(16) float CpT[2][16][132];   // panel cols, [m][r]
    __shared__ __align__(16) float Rp [2][16][128];   // panel rows, [j][c]
    __shared__ __align__(16) float Dw [8][16][20];    // per-wave Dinv scratch:
                                                      // Dw[w][j][m] = Dinv[m][j]

    const int b = blockIdx.x;
    const float* __restrict__ X = prim + b * NMAT;
    const int t  = threadIdx.x;
    const int c  = t & 127;          // owned column
    const int q  = t >> 7;           // row quarter (wave-uniform)
    const int r0 = q << 5;           // owns rows r0..r0+31
    const int w  = t >> 6;           // wave id
    const int cp = t & 15;           // D-column replica index

    for (int idx4 = t; idx4 < 4096; idx4 += 512) {
        int gi = idx4 << 2;
        float4 v = *(const float4*)(X + gi);
        int r = gi >> 7, cc = gi & 127;
        float* p = &Xs[r * 129 + cc];
        p[0] = v.x; p[1] = v.y; p[2] = v.z; p[3] = v.w;
    }
    __syncthreads();

    // reg[i] = N[r0+i][c];  A = tril(X) - tril(X)^T
    float reg[32];
    #pragma unroll
    for (int i = 0; i < 32; ++i) {
        int r  = r0 + i;
        int mx = r > c ? r : c;
        int mn = r ^ c ^ mx;
        float x = Xs[mx * 129 + mn];
        reg[i] = (r == c) ? 1.0f : (r > c ? 0.5f * x : -0.5f * x);
    }

    #pragma unroll 1                              // I$: one resident body, 8x reuse
    for (int s = 0; s < 8; ++s) {
        const int  p     = s & 1;
        const int  k0    = s << 4;
        const int  q0    = s >> 1;                // quarter holding rows K
        const bool lo    = (s & 1) == 0;          // rows K at reg[0..16) or reg[16..32)
        const bool panel = (c >= k0) && (c < k0 + 16);

        // ---- publish pre-step panel into buffer p (other buffer still live)
        if (panel) {
            const int m = c - k0;
            #pragma unroll
            for (int i = 0; i < 32; i += 4)
                *(float4*)&CpT[p][m][r0 + i] =
                    make_float4(reg[i], reg[i+1], reg[i+2], reg[i+3]);
        }
        if (q == q0) {
            if (lo) {
                #pragma unroll
                for (int j = 0; j < 16; ++j) Rp[p][j][c] = reg[j];
            } else {
                #pragma unroll
                for (int j = 0; j < 16; ++j) Rp[p][j][c] = reg[16 + j];
            }
        }
        __syncthreads();                          // the ONLY barrier this step

        // ---- per-wave 16-lane replicated GJ inverse of D (16x16), registers
        float dd[16];
        #pragma unroll
        for (int j = 0; j < 16; ++j) dd[j] = Rp[p][j][k0 + cp];
        #pragma unroll
        for (int k = 0; k < 16; ++k) {
            float dkk  = __shfl(dd[k], k);        // D[k][k]
            float dinv = 1.0f / dkk;
            float cv[16];
            #pragma unroll
            for (int i = 0; i < 16; ++i) cv[i] = __shfl(dd[i], k);  // col k
            const bool own = (cp == k);
            const float sv = dd[k] * dinv;        // non-owner: new row-k value
            #pragma unroll
            for (int i = 0; i < 16; ++i) {
                float nv = own ? (-dd[i] * dinv) : fmaf(-cv[i], sv, dd[i]);
                dd[i] = (i == k) ? (own ? dinv : sv) : nv;
            }
        }
        // dd[j] = Dinv[j][cp].  Stash to this wave's scratch (wave-coherent,
        // compiler inserts lgkmcnt before the dependent reads below).
        if ((t & 63) < 16) {
            *(float4*)&Dw[w][cp][0]  = make_float4(dd[0], dd[1], dd[2], dd[3]);
            *(float4*)&Dw[w][cp][4]  = make_float4(dd[4], dd[5], dd[6], dd[7]);
            *(float4*)&Dw[w][cp][8]  = make_float4(dd[8], dd[9], dd[10], dd[11]);
            *(float4*)&Dw[w][cp][12] = make_float4(dd[12], dd[13], dd[14], dd[15]);
        }

        // ---- coefficients
        float coeff[16];
        if (!panel) {                             // (Dinv*R)[m][c]
            float rr[16];
            #pragma unroll
            for (int j = 0; j < 16; ++j) rr[j] = Rp[p][j][c];
            #pragma unroll
            for (int j = 0; j < 16; ++j) coeff[j] = 0.0f;
            #pragma unroll
            for (int j = 0; j < 16; ++j) {
                float rpj = rr[j];
                #pragma unroll
                for (int mq = 0; mq < 16; mq += 4) {
                    float4 dv = *(const float4*)&Dw[w][j][mq];   // broadcast
                    coeff[mq+0] = fmaf(dv.x, rpj, coeff[mq+0]);
                    coeff[mq+1] = fmaf(dv.y, rpj, coeff[mq+1]);
                    coeff[mq+2] = fmaf(dv.z, rpj, coeff[mq+2]);
                    coeff[mq+3] = fmaf(dv.w, rpj, coeff[mq+3]);
                }
            }
        } else {                                  // Dinv[:, c-k0]; c-k0 == cp!
            #pragma unroll
            for (int j = 0; j < 16; ++j) coeff[j] = dd[j];
            #pragma unroll
            for (int i = 0; i < 32; ++i) reg[i] = 0.0f;   // col block = -C*Dinv
        }

        // ---- rank-16 update: reg[i] -= sum_m C[r0+i][m] * coeff[m]
        #pragma unroll
        for (int m = 0; m < 16; ++m) {
            float cm = coeff[m];
            #pragma unroll
            for (int i = 0; i < 32; i += 4) {
                float4 c4 = *(const float4*)&CpT[p][m][r0 + i];   // broadcast
                reg[i+0] = fmaf(-c4.x, cm, reg[i+0]);
                reg[i+1] = fmaf(-c4.y, cm, reg[i+1]);
                reg[i+2] = fmaf(-c4.z, cm, reg[i+2]);
                reg[i+3] = fmaf(-c4.w, cm, reg[i+3]);
            }
        }
        // rows K: W[K,J'] = Dinv*R (non-panel), W[K,K] = Dinv (panel)
        if (q == q0) {
            if (lo) {
                #pragma unroll
                for (int j = 0; j < 16; ++j) reg[j] = coeff[j];
            } else {
                #pragma unroll
                for (int j = 0; j < 16; ++j) reg[16 + j] = coeff[j];
            }
        }
        // next step publishes into buffer p^1; its barrier guards the reuse
    }

    float* __restrict__ out = QT + b * NMAT;
    #pragma unroll
    for (int i = 0; i < 32; ++i) {
        int r = r0 + i;
        out[r * HALF + c] = 2.0f * reg[i] - (r == c ? 1.0f : 0.0f);
    }
}

// ---------------------------------------------------------------------------
// K2: path table via tree recursion:
//   P[v] = P[(v&127)|128] * prod_{d=7}^{L-2} Q^T_{bit_d(v)}  (same op order
// as reference -> fp-identical).  base: rows [0,256) direct; expand: rest.
// ---------------------------------------------------------------------------
__global__ __launch_bounds__(256) void path_steps(const float* __restrict__ QT,
                                                  const float* __restrict__ ident,
                                                  float* __restrict__ P,
                                                  int vbase, int d0) {
    __shared__ float vs[2][8][HALF];
    const int t    = threadIdx.x;
    const int rg   = t >> 5;                 // row in block (0..7)
    const int jj   = (t & 31) << 2;          // 4-col chunk
    const int v    = vbase + (blockIdx.x << 3) + rg;
    const int vmax = vbase + (blockIdx.x << 3) + 7;

    float4 sv;
    if (d0 == 0) {
        sv = *(const float4*)&ident[jj];
    } else {
        const int u = (v & 127) | 128;       // bitlen-8 ancestor (base row)
        sv = *(const float4*)&P[u * HALF + jj];
    }
    *(float4*)&vs[0][rg][jj] = sv;
    __syncthreads();

    int cur = 0;
    for (int d = d0; d < 13; ++d) {
        if ((vmax >> (d + 1)) == 0) break;           // block-uniform
        const bool valid = (v >> (d + 1)) > 0;       // row still on its path?
        const float* __restrict__ Qm = QT + (((v >> d) & 1) ? NMAT : 0);
        float4 acc = make_float4(0.f, 0.f, 0.f, 0.f);
        #pragma unroll 4
        for (int cc = 0; cc < 128; cc += 4) {
            float4 v4 = *(const float4*)&vs[cur][rg][cc];   // 2-addr bcast (free)
            float4 q0 = *(const float4*)&Qm[(cc+0)*HALF + jj];
            float4 q1 = *(const float4*)&Qm[(cc+1)*HALF + jj];
            float4 q2 = *(const float4*)&Qm[(cc+2)*HALF + jj];
            float4 q3 = *(const float4*)&Qm[(cc+3)*HALF + jj];
            acc.x = fmaf(v4.x,q0.x, fmaf(v4.y,q1.x, fmaf(v4.z,q2.x, fmaf(v4.w,q3.x, acc.x))));
            acc.y = fmaf(v4.x,q0.y, fmaf(v4.y,q1.y, fmaf(v4.z,q2.y, fmaf(v4.w,q3.y, acc.y))));
            acc.z = fmaf(v4.x,q0.z, fmaf(v4.y,q1.z, fmaf(v4.z,q2.z, fmaf(v4.w,q3.z, acc.z))));
            acc.w = fmaf(v4.x,q0.w, fmaf(v4.y,q1.w, fmaf(v4.z,q2.w, fmaf(v4.w,q3.w, acc.w))));
        }
        if (!valid) acc = *(const float4*)&vs[cur][rg][jj];  // carry forward
        *(float4*)&vs[cur ^ 1][rg][jj] = acc;   // other buffer: no WAR
        __syncthreads();
        cur ^= 1;
    }
    *(float4*)&P[v * HALF + jj] = *(const float4*)&vs[cur][rg][jj];
}

// ---------------------------------------------------------------------------
// K3: emit [B,S,256] = content ++ pos.  One wave per token; branchless source
// select + nontemporal float4 stores (134 MB streamed, never re-read).
// ---------------------------------------------------------------------------
__global__ __launch_bounds__(256) void emit_out(const int* __restrict__ tt,
                                                const int* __restrict__ tv,
                                                const int* __restrict__ np,
                                                const float* __restrict__ P,
                                                const float* __restrict__ emb,
                                                float* __restrict__ out) {
    const int i  = (blockIdx.x << 2) + (threadIdx.x >> 6);
    const int jj = (threadIdx.x & 63) << 2;
    float4 val;
    if (jj < 128) {
        const int ty = tt[i], v = tv[i];
        const float* src;
        bool zero = false;
        if (ty == 0)      src = emb + jj;
        else if (ty == 1) src = emb + (v + 1) * HALF + jj;
        else if (ty == 2) src = emb + (v + 5) * HALF + jj;
        else if (ty == 4) {
            int vc = v < 0 ? 0 : (v > 4095 ? 4095 : v);
            src = P + vc * HALF + jj;
        } else {                       // ty == 3
            src = emb + 10 * HALF + jj;
            zero = (v != -1);
        }
        val = *(const float4*)src;
        if (zero) val = make_float4(0.f, 0.f, 0.f, 0.f);
    } else {
        val = *(const float4*)&P[np[i] * HALF + (jj - 128)];
    }
    __builtin_nontemporal_store(val.x, &out[i * 256 + jj + 0]);
    __builtin_nontemporal_store(val.y, &out[i * 256 + jj + 1]);
    __builtin_nontemporal_store(val.z, &out[i * 256 + jj + 2]);
    __builtin_nontemporal_store(val.w, &out[i * 256 + jj + 3]);
}

extern "C" void kernel_launch(void* const* d_in, const int* in_sizes, int n_in,
                              void* d_out, int out_size, void* d_ws, size_t ws_size,
                              hipStream_t stream) {
    const int*   token_types = (const int*)  d_in[0];
    const int*   token_vals  = (const int*)  d_in[1];
    const int*   node_pos    = (const int*)  d_in[2];
    const float* prim        = (const float*)d_in[3];
    const float* ident       = (const float*)d_in[4];
    const float* emb         = (const float*)d_in[5];
    float* out = (float*)d_out;

    // workspace: QT[2][128][128] | (gap) | P[4096][128]
    float* QT = (float*)d_ws;
    float* P  = (float*)((char*)d_ws + 262144);

    cayley_qt  <<<2,   512, 0, stream>>>(prim, QT);
    path_steps <<<32,  256, 0, stream>>>(QT, ident, P, 0,   0);   // rows [0,256)
    path_steps <<<480, 256, 0, stream>>>(QT, ident, P, 256, 7);   // rows [256,4096)
    emit_out   <<<NTOK / 4, 256, 0, stream>>>(token_types, token_vals, node_pos,
                                              P, emb, out);
}